// Round 7
// baseline (103.026 us; speedup 1.0000x reference)
//
#include <hip/hip_runtime.h>
#include <hip/hip_bf16.h>
#include <math.h>

#define B_  4
#define S_  4096
#define D_  1024
#define KD_ 128

typedef __attribute__((ext_vector_type(8))) short short8;
typedef __attribute__((ext_vector_type(4))) float f32x4;
typedef __attribute__((ext_vector_type(4))) unsigned short us4;

__device__ __forceinline__ unsigned short f2bf(float f) {
    __hip_bfloat16 h = __float2bfloat16(f);
    return *reinterpret_cast<unsigned short*>(&h);
}

__device__ __forceinline__ f32x4 mfma_bf16(short8 a, short8 b, f32x4 c) {
    return __builtin_amdgcn_mfma_f32_16x16x32_bf16(a, b, c, 0, 0, 0);
}

__device__ __forceinline__ void g2l16(const void* g, void* l) {
    __builtin_amdgcn_global_load_lds(
        (const __attribute__((address_space(1))) unsigned int*)g,
        (__attribute__((address_space(3))) unsigned int*)l, 16, 0, 0);
}

// ---------------------------------------------------------------------------
// Convert weights [D,128] fp32 -> Wt [3][128][D] bf16 (transposed).
// Q weight folds in log2(e)/sqrt(128) so softmax can use native exp2.
__global__ void convert_w_kernel(const float* __restrict__ wq,
                                 const float* __restrict__ wk,
                                 const float* __restrict__ wv,
                                 unsigned short* __restrict__ wt) {
    int t = blockIdx.x * 256 + threadIdx.x;       // 0..49151
    int w = t >> 14;
    int r = t & 16383;
    int n = r & 127;
    int k8 = r >> 7;                               // 0..127
    const float* src = (w == 0) ? wq : (w == 1) ? wk : wv;
    float scale = (w == 0) ? 0.12751725551033443f : 1.0f;  // log2e/sqrt(128)
    short8 v;
#pragma unroll
    for (int i = 0; i < 8; ++i)
        v[i] = (short)f2bf(src[(size_t)(k8 * 8 + i) * KD_ + n] * scale);
    *reinterpret_cast<short8*>(&wt[(size_t)w * KD_ * D_ + (size_t)n * D_ + k8 * 8]) = v;
}

// ---------------------------------------------------------------------------
// Projection GEMM: C[16384,128] = X[16384,1024] @ W.  NT form with Wt[128][1024].
__global__ __launch_bounds__(256) void proj_kernel(
        const float* __restrict__ X, const unsigned short* __restrict__ Wt,
        unsigned short* __restrict__ Qo, unsigned short* __restrict__ Ko,
        unsigned short* __restrict__ Vt) {
    const int mtile = blockIdx.x;
    const int which = blockIdx.y;
    const int m0 = mtile * 128;
    const int tid = threadIdx.x;
    const int lane = tid & 63;
    const int wid = tid >> 6;
    const int wr = wid >> 1, wc = wid & 1;
    const int l15 = lane & 15, l4 = lane >> 4;

    __shared__ __align__(16) unsigned short Asm[128 * 64];
    __shared__ __align__(16) unsigned short Bsm[128 * 64];
    __shared__ __align__(16) unsigned short Tsm[128 * 128];

    const unsigned short* W = Wt + (size_t)which * KD_ * D_;

    f32x4 acc[4][4];
#pragma unroll
    for (int r = 0; r < 4; ++r)
#pragma unroll
        for (int c = 0; c < 4; ++c) acc[r][c] = (f32x4)0.0f;

    for (int k0 = 0; k0 < D_; k0 += 64) {
#pragma unroll
        for (int i = 0; i < 8; ++i) {
            int f = tid + i * 256;
            int row = f >> 4, c4 = f & 15;
            float4 xv = *reinterpret_cast<const float4*>(
                &X[(size_t)(m0 + row) * D_ + k0 + c4 * 4]);
            us4 h;
            h.x = f2bf(xv.x); h.y = f2bf(xv.y); h.z = f2bf(xv.z); h.w = f2bf(xv.w);
            *reinterpret_cast<us4*>(&Asm[row * 64 + c4 * 4]) = h;
        }
#pragma unroll
        for (int i = 0; i < 4; ++i) {
            int g = tid + i * 256;
            int n = g >> 3, c8 = g & 7;
            *reinterpret_cast<short8*>(&Bsm[n * 64 + c8 * 8]) =
                *reinterpret_cast<const short8*>(&W[(size_t)n * D_ + k0 + c8 * 8]);
        }
        __syncthreads();

        short8 a[4][2], b[4][2];
#pragma unroll
        for (int rt = 0; rt < 4; ++rt)
#pragma unroll
            for (int kc = 0; kc < 2; ++kc)
                a[rt][kc] = *reinterpret_cast<const short8*>(
                    &Asm[(wr * 64 + rt * 16 + l15) * 64 + kc * 32 + l4 * 8]);
#pragma unroll
        for (int ct = 0; ct < 4; ++ct)
#pragma unroll
            for (int kc = 0; kc < 2; ++kc)
                b[ct][kc] = *reinterpret_cast<const short8*>(
                    &Bsm[(wc * 64 + ct * 16 + l15) * 64 + kc * 32 + l4 * 8]);
#pragma unroll
        for (int kc = 0; kc < 2; ++kc)
#pragma unroll
            for (int rt = 0; rt < 4; ++rt)
#pragma unroll
                for (int ct = 0; ct < 4; ++ct)
                    acc[rt][ct] = mfma_bf16(a[rt][kc], b[ct][kc], acc[rt][ct]);
        __syncthreads();
    }

    if (which < 2) {
        unsigned short* O = (which == 0) ? Qo : Ko;
#pragma unroll
        for (int rt = 0; rt < 4; ++rt)
#pragma unroll
            for (int ct = 0; ct < 4; ++ct)
#pragma unroll
                for (int j = 0; j < 4; ++j) {
                    int row = m0 + wr * 64 + rt * 16 + l4 * 4 + j;
                    int col = wc * 64 + ct * 16 + l15;
                    O[(size_t)row * KD_ + col] = f2bf(acc[rt][ct][j]);
                }
    } else {
#pragma unroll
        for (int rt = 0; rt < 4; ++rt)
#pragma unroll
            for (int ct = 0; ct < 4; ++ct)
#pragma unroll
                for (int j = 0; j < 4; ++j) {
                    int row = wr * 64 + rt * 16 + l4 * 4 + j;  // s-local
                    int col = wc * 64 + ct * 16 + l15;          // n
                    Tsm[col * 128 + row] = f2bf(acc[rt][ct][j]);
                }
        __syncthreads();
        int bb = m0 >> 12;
        int s0 = m0 & 4095;
#pragma unroll
        for (int i = 0; i < 8; ++i) {
            int g = tid + i * 256;
            int n = g >> 4, s8 = g & 15;
            *reinterpret_cast<short8*>(
                &Vt[(size_t)bb * KD_ * S_ + (size_t)n * S_ + s0 + s8 * 8]) =
                *reinterpret_cast<short8*>(&Tsm[n * 128 + s8 * 8]);
        }
    }
}

// ---------------------------------------------------------------------------
// Flash attention: 256 blocks, 512 threads = 4 KV-split groups x 2 waves,
// wave owns 32 q-rows. XCD swizzle keeps one batch's K/V per XCD (L2-resident,
// R6-verified: FETCH 34.9->10.3 MB). R7: T4 counted-vmcnt pipeline -- raw
// s_barriers, prefetch loads stay in flight across the barrier (vmcnt(8)),
// no vmcnt(0) drain inside the loop.
__global__ __launch_bounds__(512, 2) void attn_kernel(
        const unsigned short* __restrict__ Q,
        const unsigned short* __restrict__ Kb,
        const unsigned short* __restrict__ Vt,
        float* __restrict__ Out) {
    const int bid = blockIdx.x;       // 0..255
    const int b  = bid & 3;           // xcd = bid%8 -> xcd&3 == b: 1 batch/XCD
    const int qt = bid >> 2;          // 0..63
    const int tid = threadIdx.x;
    const int lane = tid & 63;
    const int wid = tid >> 6;         // 0..7
    const int grp = wid >> 1;         // 0..3  (KV-split group)
    const int wg  = wid & 1;          // wave within group
    const int q0 = qt * 64;
    const int l15 = lane & 15, l4 = lane >> 4;

    // manual LDS carve: K 64K | V 64K | P 16K  (merge scratch reuses K+V)
    __shared__ __align__(16) unsigned char lds_raw[147456];
    unsigned short* KsmA = (unsigned short*)lds_raw;             // [4][2][32*128]
    unsigned short* VsmA = (unsigned short*)(lds_raw + 65536);   // [4][2][128*32]
    unsigned short* Psm  = (unsigned short*)(lds_raw + 131072);  // [8][32*32]

    // Q fragments: 32 q-rows per wave (both sub-tiles a=0,1)
    short8 aq[2][4];
    {
#pragma unroll
        for (int a = 0; a < 2; ++a) {
            const unsigned short* qrow =
                Q + ((size_t)(b * S_ + q0 + wg * 32 + a * 16 + l15)) * KD_;
#pragma unroll
            for (int kc = 0; kc < 4; ++kc)
                aq[a][kc] = *reinterpret_cast<const short8*>(&qrow[kc * 32 + l4 * 8]);
        }
    }

    f32x4 acc[2][8];
#pragma unroll
    for (int a = 0; a < 2; ++a)
#pragma unroll
        for (int i = 0; i < 8; ++i) acc[a][i] = (f32x4)0.0f;
    float lsum[2][4] = {{0,0,0,0},{0,0,0,0}};

    const unsigned short* Kbase = Kb + (size_t)b * S_ * KD_;
    const unsigned short* Vbase = Vt + (size_t)b * KD_ * S_;

    unsigned short* Kgrp = KsmA + grp * 2 * 4096;
    unsigned short* Vgrp = VsmA + grp * 2 * 4096;

    // stage K[32][128] + V[128][32] tile kt into buf (2 waves cooperate)
    // 8 global_load_lds per wave per call.
    auto STAGE = [&](int buf, int kt) {
#pragma unroll
        for (int i = 0; i < 4; ++i) {
            int d = i * 128 + wg * 64 + lane;          // K granule 0..511
            int row = d >> 4, c = d & 15;              // 16 granules per 128-row
            g2l16(&Kbase[(size_t)(kt * 32 + row) * KD_ + ((c ^ (row & 7)) * 8)],
                  &Kgrp[(buf * 512 + i * 128 + wg * 64) * 8]);
        }
#pragma unroll
        for (int i = 0; i < 4; ++i) {
            int d = i * 128 + wg * 64 + lane;          // V granule 0..511
            int row = d >> 2, c = d & 3;               // 4 granules per 32-row
            g2l16(&Vbase[(size_t)row * S_ + kt * 32 + ((c ^ ((row >> 1) & 3)) * 8)],
                  &Vgrp[(buf * 512 + i * 128 + wg * 64) * 8]);
        }
    };

    int cur = 0;
    STAGE(0, grp);
    asm volatile("s_waitcnt vmcnt(0)" ::: "memory");
    __builtin_amdgcn_s_barrier();
    __builtin_amdgcn_sched_barrier(0);

    for (int it = 0; it < 32; ++it) {
        // issue next-tile prefetch, then wait only for the PREVIOUS tile's
        // loads (counted vmcnt) -- prefetch stays in flight across barrier.
        if (it < 31) {
            STAGE(cur ^ 1, (it + 1) * 4 + grp);
            asm volatile("s_waitcnt vmcnt(8)" ::: "memory");
        } else {
            asm volatile("s_waitcnt vmcnt(0)" ::: "memory");
        }
        __builtin_amdgcn_s_barrier();      // RAW: tile[cur] ready for all waves
        __builtin_amdgcn_sched_barrier(0); // pin: no ds_read hoisted above

        const unsigned short* ksm = Kgrp + cur * 4096;
        const unsigned short* vsm = Vgrp + cur * 4096;

        // S = Q K^T : 32 q-rows x 32 kv-cols per wave
        f32x4 sf[2][2];
#pragma unroll
        for (int a = 0; a < 2; ++a)
#pragma unroll
            for (int ct = 0; ct < 2; ++ct) sf[a][ct] = (f32x4)0.0f;
        __builtin_amdgcn_s_setprio(1);
#pragma unroll
        for (int kc = 0; kc < 4; ++kc)
#pragma unroll
            for (int ct = 0; ct < 2; ++ct) {
                int row = ct * 16 + l15;
                short8 bk = *reinterpret_cast<const short8*>(
                    &ksm[row * 128 + (((kc * 4 + l4) ^ (row & 7)) * 8)]);
#pragma unroll
                for (int a = 0; a < 2; ++a)
                    sf[a][ct] = mfma_bf16(aq[a][kc], bk, sf[a][ct]);
            }
        __builtin_amdgcn_s_setprio(0);

        // p = exp2(s_pre); accumulate per-lane row sums; P -> LDS (swizzled)
#pragma unroll
        for (int a = 0; a < 2; ++a)
#pragma unroll
            for (int ct = 0; ct < 2; ++ct)
#pragma unroll
                for (int j = 0; j < 4; ++j) {
                    float p = exp2f(sf[a][ct][j]);
                    lsum[a][j] += p;
                    int r = a * 16 + l4 * 4 + j;
                    int cswz = ((ct * 2 + (l15 >> 3)) ^ ((r >> 1) & 3)) * 8 + (l15 & 7);
                    Psm[wid * 1024 + r * 32 + cswz] = f2bf(p);
                }

        // O += P V
        __builtin_amdgcn_s_setprio(1);
        short8 pa[2];
#pragma unroll
        for (int a = 0; a < 2; ++a) {
            int r = a * 16 + l15;
            pa[a] = *reinterpret_cast<const short8*>(
                &Psm[wid * 1024 + r * 32 + ((l4 ^ ((r >> 1) & 3)) * 8)]);
        }
#pragma unroll
        for (int c8 = 0; c8 < 8; ++c8) {
            int row = c8 * 16 + l15;
            short8 bv = *reinterpret_cast<const short8*>(
                &vsm[row * 32 + ((l4 ^ ((row >> 1) & 3)) * 8)]);
#pragma unroll
            for (int a = 0; a < 2; ++a)
                acc[a][c8] = mfma_bf16(pa[a], bv, acc[a][c8]);
        }
        __builtin_amdgcn_s_setprio(0);

        __builtin_amdgcn_sched_barrier(0); // pin: reads complete before WAR
        __builtin_amdgcn_s_barrier();      // WAR: all waves done reading cur
        cur ^= 1;
    }

    // full row sums (cols were spread over 16 lanes)
#pragma unroll
    for (int a = 0; a < 2; ++a)
#pragma unroll
        for (int j = 0; j < 4; ++j) {
            float t = lsum[a][j];
            t += __shfl_xor(t, 1);
            t += __shfl_xor(t, 2);
            t += __shfl_xor(t, 4);
            t += __shfl_xor(t, 8);
            lsum[a][j] = t;
        }

    // 4-way merge through LDS (scratch overlays K+V staging regions)
    float* scratch = (float*)lds_raw;                 // 3 * 64*128 f32 = 96 KiB
    float* lsumS   = (float*)(lds_raw + 98304);       // 3 * 64 f32
    __syncthreads();
    if (grp >= 1) {
        int base = (grp - 1) * 8192;
#pragma unroll
        for (int a = 0; a < 2; ++a)
#pragma unroll
            for (int j = 0; j < 4; ++j) {
                int row = wg * 32 + a * 16 + l4 * 4 + j;
#pragma unroll
                for (int c8 = 0; c8 < 8; ++c8)
                    scratch[base + row * 128 + c8 * 16 + l15] = acc[a][c8][j];
                if (l15 == 0) lsumS[(grp - 1) * 64 + row] = lsum[a][j];
            }
    }
    __syncthreads();
    if (grp == 0) {
        float* Ob = Out + (size_t)b * S_ * KD_;
#pragma unroll
        for (int a = 0; a < 2; ++a)
#pragma unroll
            for (int j = 0; j < 4; ++j) {
                int row = wg * 32 + a * 16 + l4 * 4 + j;
                float l = lsum[a][j] + lsumS[row] + lsumS[64 + row] + lsumS[128 + row];
                float inv = 1.0f / l;
#pragma unroll
                for (int c8 = 0; c8 < 8; ++c8) {
                    int idx = row * 128 + c8 * 16 + l15;
                    float o = acc[a][c8][j] + scratch[idx] + scratch[8192 + idx] +
                              scratch[16384 + idx];
                    Ob[(size_t)(q0 + row) * KD_ + c8 * 16 + l15] = o * inv;
                }
            }
    }
}

// ---------------------------------------------------------------------------
extern "C" void kernel_launch(void* const* d_in, const int* in_sizes, int n_in,
                              void* d_out, int out_size, void* d_ws, size_t ws_size,
                              hipStream_t stream) {
    const float* X  = (const float*)d_in[0];
    const float* Wq = (const float*)d_in[1];
    const float* Wk = (const float*)d_in[2];
    const float* Wv = (const float*)d_in[3];
    float* Out = (float*)d_out;

    unsigned short* Wt  = (unsigned short*)d_ws;                    // 786432 B
    unsigned short* Q16 = (unsigned short*)((char*)d_ws + 786432);  // 4 MiB
    unsigned short* K16 = Q16 + (size_t)16384 * 128;                // 4 MiB
    unsigned short* V16 = K16 + (size_t)16384 * 128;                // 4 MiB (Vt)

    hipLaunchKernelGGL(convert_w_kernel, dim3(192), dim3(256), 0, stream,
                       Wq, Wk, Wv, Wt);
    hipLaunchKernelGGL(proj_kernel, dim3(128, 3), dim3(256), 0, stream,
                       X, Wt, Q16, K16, V16);
    hipLaunchKernelGGL(attn_kernel, dim3(256), dim3(512), 0, stream,
                       Q16, K16, V16, Out);
}

// Round 8
// 98.229 us; speedup vs baseline: 1.0488x; 1.0488x over previous
//
#include <hip/hip_runtime.h>
#include <hip/hip_bf16.h>
#include <math.h>

#define B_  4
#define S_  4096
#define D_  1024
#define KD_ 128

typedef __attribute__((ext_vector_type(8))) short short8;
typedef __attribute__((ext_vector_type(4))) float f32x4;
typedef __attribute__((ext_vector_type(16))) float f32x16;
typedef __attribute__((ext_vector_type(4))) unsigned short us4;
typedef __attribute__((ext_vector_type(4))) unsigned int u32x4;

__device__ __forceinline__ unsigned short f2bf(float f) {
    __hip_bfloat16 h = __float2bfloat16(f);
    return *reinterpret_cast<unsigned short*>(&h);
}

__device__ __forceinline__ f32x4 mfma_bf16(short8 a, short8 b, f32x4 c) {
    return __builtin_amdgcn_mfma_f32_16x16x32_bf16(a, b, c, 0, 0, 0);
}

__device__ __forceinline__ f32x16 mfma32_bf16(short8 a, short8 b, f32x16 c) {
    return __builtin_amdgcn_mfma_f32_32x32x16_bf16(a, b, c, 0, 0, 0);
}

__device__ __forceinline__ unsigned int cvt_pk_bf16(float lo, float hi_) {
    unsigned int r;
    asm("v_cvt_pk_bf16_f32 %0, %1, %2" : "=v"(r) : "v"(lo), "v"(hi_));
    return r;
}

__device__ __forceinline__ void g2l16(const void* g, void* l) {
    __builtin_amdgcn_global_load_lds(
        (const __attribute__((address_space(1))) unsigned int*)g,
        (__attribute__((address_space(3))) unsigned int*)l, 16, 0, 0);
}

// ---------------------------------------------------------------------------
// Convert weights [D,128] fp32 -> Wt [3][128][D] bf16 (transposed).
// Q weight folds in log2(e)/sqrt(128) so softmax can use native exp2.
__global__ void convert_w_kernel(const float* __restrict__ wq,
                                 const float* __restrict__ wk,
                                 const float* __restrict__ wv,
                                 unsigned short* __restrict__ wt) {
    int t = blockIdx.x * 256 + threadIdx.x;       // 0..49151
    int w = t >> 14;
    int r = t & 16383;
    int n = r & 127;
    int k8 = r >> 7;                               // 0..127
    const float* src = (w == 0) ? wq : (w == 1) ? wk : wv;
    float scale = (w == 0) ? 0.12751725551033443f : 1.0f;  // log2e/sqrt(128)
    short8 v;
#pragma unroll
    for (int i = 0; i < 8; ++i)
        v[i] = (short)f2bf(src[(size_t)(k8 * 8 + i) * KD_ + n] * scale);
    *reinterpret_cast<short8*>(&wt[(size_t)w * KD_ * D_ + (size_t)n * D_ + k8 * 8]) = v;
}

// ---------------------------------------------------------------------------
// Projection GEMM: C[16384,128] = X[16384,1024] @ W.  NT form with Wt[128][1024].
__global__ __launch_bounds__(256) void proj_kernel(
        const float* __restrict__ X, const unsigned short* __restrict__ Wt,
        unsigned short* __restrict__ Qo, unsigned short* __restrict__ Ko,
        unsigned short* __restrict__ Vt) {
    const int mtile = blockIdx.x;
    const int which = blockIdx.y;
    const int m0 = mtile * 128;
    const int tid = threadIdx.x;
    const int lane = tid & 63;
    const int wid = tid >> 6;
    const int wr = wid >> 1, wc = wid & 1;
    const int l15 = lane & 15, l4 = lane >> 4;

    __shared__ __align__(16) unsigned short Asm[128 * 64];
    __shared__ __align__(16) unsigned short Bsm[128 * 64];
    __shared__ __align__(16) unsigned short Tsm[128 * 128];

    const unsigned short* W = Wt + (size_t)which * KD_ * D_;

    f32x4 acc[4][4];
#pragma unroll
    for (int r = 0; r < 4; ++r)
#pragma unroll
        for (int c = 0; c < 4; ++c) acc[r][c] = (f32x4)0.0f;

    for (int k0 = 0; k0 < D_; k0 += 64) {
#pragma unroll
        for (int i = 0; i < 8; ++i) {
            int f = tid + i * 256;
            int row = f >> 4, c4 = f & 15;
            float4 xv = *reinterpret_cast<const float4*>(
                &X[(size_t)(m0 + row) * D_ + k0 + c4 * 4]);
            us4 h;
            h.x = f2bf(xv.x); h.y = f2bf(xv.y); h.z = f2bf(xv.z); h.w = f2bf(xv.w);
            *reinterpret_cast<us4*>(&Asm[row * 64 + c4 * 4]) = h;
        }
#pragma unroll
        for (int i = 0; i < 4; ++i) {
            int g = tid + i * 256;
            int n = g >> 3, c8 = g & 7;
            *reinterpret_cast<short8*>(&Bsm[n * 64 + c8 * 8]) =
                *reinterpret_cast<const short8*>(&W[(size_t)n * D_ + k0 + c8 * 8]);
        }
        __syncthreads();

        short8 a[4][2], b[4][2];
#pragma unroll
        for (int rt = 0; rt < 4; ++rt)
#pragma unroll
            for (int kc = 0; kc < 2; ++kc)
                a[rt][kc] = *reinterpret_cast<const short8*>(
                    &Asm[(wr * 64 + rt * 16 + l15) * 64 + kc * 32 + l4 * 8]);
#pragma unroll
        for (int ct = 0; ct < 4; ++ct)
#pragma unroll
            for (int kc = 0; kc < 2; ++kc)
                b[ct][kc] = *reinterpret_cast<const short8*>(
                    &Bsm[(wc * 64 + ct * 16 + l15) * 64 + kc * 32 + l4 * 8]);
#pragma unroll
        for (int kc = 0; kc < 2; ++kc)
#pragma unroll
            for (int rt = 0; rt < 4; ++rt)
#pragma unroll
                for (int ct = 0; ct < 4; ++ct)
                    acc[rt][ct] = mfma_bf16(a[rt][kc], b[ct][kc], acc[rt][ct]);
        __syncthreads();
    }

    if (which < 2) {
        unsigned short* O = (which == 0) ? Qo : Ko;
#pragma unroll
        for (int rt = 0; rt < 4; ++rt)
#pragma unroll
            for (int ct = 0; ct < 4; ++ct)
#pragma unroll
                for (int j = 0; j < 4; ++j) {
                    int row = m0 + wr * 64 + rt * 16 + l4 * 4 + j;
                    int col = wc * 64 + ct * 16 + l15;
                    O[(size_t)row * KD_ + col] = f2bf(acc[rt][ct][j]);
                }
    } else {
#pragma unroll
        for (int rt = 0; rt < 4; ++rt)
#pragma unroll
            for (int ct = 0; ct < 4; ++ct)
#pragma unroll
                for (int j = 0; j < 4; ++j) {
                    int row = wr * 64 + rt * 16 + l4 * 4 + j;  // s-local
                    int col = wc * 64 + ct * 16 + l15;          // n
                    Tsm[col * 128 + row] = f2bf(acc[rt][ct][j]);
                }
        __syncthreads();
        int bb = m0 >> 12;
        int s0 = m0 & 4095;
#pragma unroll
        for (int i = 0; i < 8; ++i) {
            int g = tid + i * 256;
            int n = g >> 4, s8 = g & 15;
            *reinterpret_cast<short8*>(
                &Vt[(size_t)bb * KD_ * S_ + (size_t)n * S_ + s0 + s8 * 8]) =
                *reinterpret_cast<short8*>(&Tsm[n * 128 + s8 * 8]);
        }
    }
}

// ---------------------------------------------------------------------------
// Flash attention R8: swapped-QK^T on 32x32x16 MFMA, softmax + P fully
// in-register (no P LDS round-trip). 256 blocks, 512 threads = 4 KV-split
// groups x 2 waves, wave owns 32 q-rows. KBLK=32, dbuf K[32][128]+V[128][32]
// per group, XCD swizzle (batch = bid&3). One __syncthreads per iter (R6's
// best-measured loop shape).
__global__ __launch_bounds__(512, 2) void attn_kernel(
        const unsigned short* __restrict__ Q,
        const unsigned short* __restrict__ Kb,
        const unsigned short* __restrict__ Vt,
        float* __restrict__ Out) {
    const int bid = blockIdx.x;       // 0..255
    const int b  = bid & 3;           // xcd = bid%8 -> one batch per XCD (L2)
    const int qt = bid >> 2;          // 0..63
    const int tid = threadIdx.x;
    const int lane = tid & 63;
    const int wid = tid >> 6;         // 0..7
    const int grp = wid >> 1;         // 0..3  (KV-split group)
    const int wg  = wid & 1;          // wave within group
    const int q0 = qt * 64;
    const int l31 = lane & 31;
    const int hi  = lane >> 5;        // 0,1

    // LDS: K [4][2][32*128] (64K) | V [4][2][128*32] (64K). merge overlays.
    __shared__ __align__(16) unsigned char lds_raw[131072];
    unsigned short* KsmA = (unsigned short*)lds_raw;
    unsigned short* VsmA = (unsigned short*)(lds_raw + 65536);

    // Q fragments: lane holds Q[q = q0+wg*32+l31][k = kc*16 + hi*8 .. +7]
    short8 aq[8];
    {
        const unsigned short* qrow =
            Q + ((size_t)(b * S_ + q0 + wg * 32 + l31)) * KD_;
#pragma unroll
        for (int kc = 0; kc < 8; ++kc)
            aq[kc] = *reinterpret_cast<const short8*>(&qrow[kc * 16 + hi * 8]);
    }

    f32x16 o[4];
#pragma unroll
    for (int dt = 0; dt < 4; ++dt) o[dt] = (f32x16)0.0f;
    float lsum = 0.0f;

    const unsigned short* Kbase = Kb + (size_t)b * S_ * KD_;
    const unsigned short* Vbase = Vt + (size_t)b * KD_ * S_;

    unsigned short* Kgrp = KsmA + grp * 2 * 4096;
    unsigned short* Vgrp = VsmA + grp * 2 * 4096;

    // stage K[32][128] + V[128][32] tile kt into buf (2 waves cooperate),
    // inverse-swizzled global source, linear LDS dest (rule #21).
    auto STAGE = [&](int buf, int kt) {
#pragma unroll
        for (int i = 0; i < 4; ++i) {
            int d = i * 128 + wg * 64 + lane;          // K granule 0..511
            int row = d >> 4, c = d & 15;              // 16 granules / 128-row
            g2l16(&Kbase[(size_t)(kt * 32 + row) * KD_ + ((c ^ (row & 7)) * 8)],
                  &Kgrp[(buf * 512 + i * 128 + wg * 64) * 8]);
        }
#pragma unroll
        for (int i = 0; i < 4; ++i) {
            int d = i * 128 + wg * 64 + lane;          // V granule 0..511
            int row = d >> 2, c = d & 3;               // 4 granules / 32-row
            g2l16(&Vbase[(size_t)row * S_ + kt * 32 + ((c ^ ((row >> 1) & 3)) * 8)],
                  &Vgrp[(buf * 512 + i * 128 + wg * 64) * 8]);
        }
    };

    int cur = 0;
    STAGE(0, grp);
    __syncthreads();

    for (int it = 0; it < 32; ++it) {
        if (it < 31) STAGE(cur ^ 1, (it + 1) * 4 + grp);   // prefetch next

        const unsigned short* ksm = Kgrp + cur * 4096;
        const unsigned short* vsm = Vgrp + cur * 4096;

        // S^T = K Q^T : one 32x32 tile per wave, q = l31 lane-local.
        // A = K rows (kv=l31, k-slice hi*8), B = Q (col q=l31, k-slice hi*8).
        f32x16 sf = (f32x16)0.0f;
        __builtin_amdgcn_s_setprio(1);
#pragma unroll
        for (int kc = 0; kc < 8; ++kc) {
            short8 bk = *reinterpret_cast<const short8*>(
                &ksm[l31 * 128 + (((kc * 2 + hi) ^ (l31 & 7)) * 8)]);
            sf = mfma32_bf16(bk, aq[kc], sf);
        }
        __builtin_amdgcn_s_setprio(0);

        // p = exp2(s_pre), per-lane row sum (q fixed per lane); pack P to
        // bf16 PV A-fragments in-register: kv(r) = (r&3)+8*(r>>2)+4*hi.
        float p[16];
#pragma unroll
        for (int r = 0; r < 16; ++r) {
            p[r] = exp2f(sf[r]);
            lsum += p[r];
        }

        short8 pa[2];
#pragma unroll
        for (int c = 0; c < 2; ++c) {
            u32x4 wv;
#pragma unroll
            for (int e = 0; e < 2; ++e) {
                unsigned int X = cvt_pk_bf16(p[8 * c + 2 * e], p[8 * c + 2 * e + 1]);
                unsigned int Y = cvt_pk_bf16(p[8 * c + 4 + 2 * e], p[8 * c + 4 + 2 * e + 1]);
                unsigned int S = hi ? X : Y;
                unsigned int T = __shfl_xor(S, 32);
                wv[e]     = hi ? T : X;
                wv[2 + e] = hi ? Y : T;
            }
            pa[c] = __builtin_bit_cast(short8, wv);
        }

        // O += P V : A = P (q=l31 rows, kv-chunk c), B = Vt rows (d cols).
        __builtin_amdgcn_s_setprio(1);
#pragma unroll
        for (int c = 0; c < 2; ++c)
#pragma unroll
            for (int dt = 0; dt < 4; ++dt) {
                int row = dt * 32 + l31;
                short8 bv = *reinterpret_cast<const short8*>(
                    &vsm[row * 32 + (((c * 2 + hi) ^ ((row >> 1) & 3)) * 8)]);
                o[dt] = mfma32_bf16(pa[c], bv, o[dt]);
            }
        __builtin_amdgcn_s_setprio(0);

        __syncthreads();
        cur ^= 1;
    }

    // complete row sums: other kv half lives in lane^32 (same q)
    lsum += __shfl_xor(lsum, 32);

    // 4-way KV-split merge through LDS (overlay staging region)
    float* scratch = (float*)lds_raw;                 // 3 * 64*128 f32 = 96K
    float* lsumS   = (float*)(lds_raw + 98304);       // 4 * 64 f32
    __syncthreads();
    if (grp >= 1) {
        int base = (grp - 1) * 8192;
#pragma unroll
        for (int dt = 0; dt < 4; ++dt)
#pragma unroll
            for (int r = 0; r < 16; ++r) {
                int row = wg * 32 + (r & 3) + 8 * (r >> 2) + 4 * hi;
                scratch[base + row * 128 + dt * 32 + l31] = o[dt][r];
            }
    }
    if (hi == 0) lsumS[grp * 64 + wg * 32 + l31] = lsum;
    __syncthreads();
    if (grp == 0) {
        float* Ob = Out + (size_t)b * S_ * KD_;
#pragma unroll
        for (int r = 0; r < 16; ++r) {
            int row = wg * 32 + (r & 3) + 8 * (r >> 2) + 4 * hi;
            float inv = 1.0f / (lsumS[row] + lsumS[64 + row] +
                                lsumS[128 + row] + lsumS[192 + row]);
#pragma unroll
            for (int dt = 0; dt < 4; ++dt) {
                int col = dt * 32 + l31;
                int idx = row * 128 + col;
                float v = o[dt][r] + scratch[idx] + scratch[8192 + idx] +
                          scratch[16384 + idx];
                Ob[(size_t)(q0 + row) * KD_ + col] = v * inv;
            }
        }
    }
}

// ---------------------------------------------------------------------------
extern "C" void kernel_launch(void* const* d_in, const int* in_sizes, int n_in,
                              void* d_out, int out_size, void* d_ws, size_t ws_size,
                              hipStream_t stream) {
    const float* X  = (const float*)d_in[0];
    const float* Wq = (const float*)d_in[1];
    const float* Wk = (const float*)d_in[2];
    const float* Wv = (const float*)d_in[3];
    float* Out = (float*)d_out;

    unsigned short* Wt  = (unsigned short*)d_ws;                    // 786432 B
    unsigned short* Q16 = (unsigned short*)((char*)d_ws + 786432);  // 4 MiB
    unsigned short* K16 = Q16 + (size_t)16384 * 128;                // 4 MiB
    unsigned short* V16 = K16 + (size_t)16384 * 128;                // 4 MiB (Vt)

    hipLaunchKernelGGL(convert_w_kernel, dim3(192), dim3(256), 0, stream,
                       Wq, Wk, Wv, Wt);
    hipLaunchKernelGGL(proj_kernel, dim3(128, 3), dim3(256), 0, stream,
                       X, Wt, Q16, K16, V16);
    hipLaunchKernelGGL(attn_kernel, dim3(256), dim3(512), 0, stream,
                       Q16, K16, V16, Out);
}